// Round 1
// baseline (348.568 us; speedup 1.0000x reference)
//
#include <hip/hip_runtime.h>

// out[b,o] = sum_e ( relu(relu(x[b,e,:]@W1[e]+b1[e])@W2[e]+b2[e]) @ W3[e] + b3[e] )
// E=16, DIN=128, H=512, DOUT=64, B=8192.  94.5 GFLOP.
//
// R6 = R5 + three changes:
//  (a) Swapped-operand MFMA in L1/L2: mfma(A=W-frag, B=X/H-frag) -> D[hcol][xrow].
//      Per lane the 4 acc regs are 4 CONSECUTIVE H-columns at one row, so the
//      epilogue is 4x v_max + cvt_pk pair + ONE ds_write_b64 per (m,n) tile
//      (was 64 scalar ds_write_b16 + manual-RNE bit twiddling per epilogue).
//      Fragment READ patterns (aX/aH/wb*) are unchanged; only intrinsic arg
//      order + epilogue indexing changed. Write bank pattern verified uniform
//      (4x4B per bank per instr).
//  (b) Bias folded into accumulator init (acc = broadcast(bias), not fzero):
//      kills 128 v_add per wave; float4 bias loads are transient regs.
//  (c) XCD-affinity swizzle: 1-D grid 2048, xcd=lin&7, 2 experts per XCD ->
//      per-XCD weight set 1.4MB fits 4MB L2 (was: all 16 experts thrash L2).
//  launch_bounds (512,4) pins VGPR<=128 (the 2-blocks/CU cliff; R5 was at 124).

#define NE   16
#define NDIN 128
#define NH   512
#define NDO  64
#define NB   8192

using bf16x8 = __attribute__((ext_vector_type(8))) __bf16;
using bf16x4 = __attribute__((ext_vector_type(4))) __bf16;
using f32x4  = __attribute__((ext_vector_type(4))) float;

__device__ __forceinline__ unsigned short f2bf(float f) {
    union { float f; unsigned u; } v; v.f = f;
    unsigned r = v.u + 0x7FFFu + ((v.u >> 16) & 1u);   // RNE
    return (unsigned short)(r >> 16);
}

// compiler-fusable bf16 conversion (emits v_cvt_pk_bf16_f32 pairs)
__device__ __forceinline__ bf16x8 cvt8(float4 a, float4 b) {
    bf16x8 r;
    r[0] = (__bf16)a.x; r[1] = (__bf16)a.y; r[2] = (__bf16)a.z; r[3] = (__bf16)a.w;
    r[4] = (__bf16)b.x; r[5] = (__bf16)b.y; r[6] = (__bf16)b.z; r[7] = (__bf16)b.w;
    return r;
}

// Swizzled index (ushort units): 16B granules XOR'd by row&15 (0 conflicts measured).
__device__ __forceinline__ int shidx(int m, int n) {          // H tile, stride 512
    return m * NH + (((n >> 3) ^ (m & 15)) << 3) + (n & 7);
}
__device__ __forceinline__ int shx(int m, int n) {            // X tile, stride 128
    return m * NDIN + ((((n >> 3) ^ (m & 15)) & 15) << 3) + (n & 7);
}

// ---------------- merged prep: fp32 [e][R][C] -> bf16 [e][C][R] ----------------
__global__ __launch_bounds__(256) void prep_weights(
    const float* __restrict__ W1, const float* __restrict__ W2, const float* __restrict__ W3,
    unsigned short* __restrict__ W1t, unsigned short* __restrict__ W2t, unsigned short* __restrict__ W3t)
{
    __shared__ float tile[64][65];
    const int t = blockIdx.x, e = blockIdx.y;
    const float* src; unsigned short* dst; int R, C, tr, tc;
    if (t < 16)      { src = W1; dst = W1t; R = NDIN; C = NH;  tr = t >> 3;        tc = t & 7;  }
    else if (t < 80) { src = W2; dst = W2t; R = NH;   C = NH;  tr = (t - 16) >> 3; tc = (t - 16) & 7; }
    else             { src = W3; dst = W3t; R = NH;   C = NDO; tr = t - 80;        tc = 0;      }
    const int r0 = tr * 64, c0 = tc * 64;
    const float* s = src + (size_t)e * R * C;
    unsigned short* d = dst + (size_t)e * R * C;
    const int tt = threadIdx.x;
#pragma unroll
    for (int i = 0; i < 4; ++i) {
        int f = i * 256 + tt;
        int r = f >> 4, c4 = (f & 15) * 4;
        const float4 v = *(const float4*)(s + (size_t)(r0 + r) * C + c0 + c4);
        tile[r][c4 + 0] = v.x; tile[r][c4 + 1] = v.y;
        tile[r][c4 + 2] = v.z; tile[r][c4 + 3] = v.w;
    }
    __syncthreads();
#pragma unroll
    for (int i = 0; i < 4; ++i) {
        int f = i * 256 + tt;
        int cc = f >> 4, rb = (f & 15) * 4;
        ushort4 o;
        o.x = f2bf(tile[rb + 0][cc]);
        o.y = f2bf(tile[rb + 1][cc]);
        o.z = f2bf(tile[rb + 2][cc]);
        o.w = f2bf(tile[rb + 3][cc]);
        *(ushort4*)(d + (size_t)(c0 + cc) * R + r0 + rb) = o;
    }
}

// ---------------- fused 3-layer expert MLP: one expert x 64 rows per WG ----------------
__global__ __launch_bounds__(512, 4) void moe_fused(
    const float* __restrict__ x,            // [B][E][DIN]
    const float* __restrict__ b1,           // [E][H]
    const float* __restrict__ b2,           // [E][H]
    const float* __restrict__ b3,           // [E][DOUT]
    const unsigned short* __restrict__ W1t, // [E][H][DIN]  bf16
    const unsigned short* __restrict__ W2t, // [E][H][H]    bf16
    const unsigned short* __restrict__ W3t, // [E][DOUT][H] bf16
    float* __restrict__ out)                // [B][DOUT]  (pre-zeroed)
{
    __shared__ unsigned short sMem[64 * NDIN + 64 * NH];  // 16KB X + 64KB H = 80KB
    unsigned short* sX = sMem;
    unsigned short* sH = sMem + 64 * NDIN;

    const int tid  = threadIdx.x;
    const int wave = tid >> 6;
    const int lane = tid & 63;
    const int q    = lane >> 4;
    const int l16  = lane & 15;
    const int hi2  = l16 >> 2;
    const int lo2  = l16 & 3;
    const int qe   = (q ^ lo2) * 8;       // swizzled in-granule element offset

    // XCD-affinity decode: dispatch round-robins linear id across the 8 XCDs,
    // so xcd = lin&7.  Give each XCD 2 experts -> weight set stays L2-resident.
    const int lin = blockIdx.x;
    const int e   = ((lin & 7) << 1) | ((lin >> 3) & 1);
    const int b0  = (lin >> 4) << 6;
    const int nb  = wave * 64;

    // per-wave LDS B-frag base offsets (elements);  read addr = base + ((kt^hi2)<<5)
    int aH[4], aX[4];
#pragma unroll
    for (int m = 0; m < 4; ++m) {
        aH[m] = (m * 16 + l16) * NH   + qe;
        aX[m] = (m * 16 + l16) * NDIN + qe;
    }

    // ---- x staging (global fp32 -> bf16 swizzled LDS), W1 prologue in flight ----
    {
        const int r0 = tid >> 4, c8 = (tid & 15) * 8;
        const float* p0 = x + ((size_t)(b0 + r0)      * NE + e) * NDIN + c8;
        const float* p1 = x + ((size_t)(b0 + 32 + r0) * NE + e) * NDIN + c8;
        float4 u0 = *(const float4*)p0, u1 = *(const float4*)(p0 + 4);
        float4 u2 = *(const float4*)p1, u3 = *(const float4*)(p1 + 4);
        *(bf16x8*)&sX[shx(r0, c8)]      = cvt8(u0, u1);
        *(bf16x8*)&sX[shx(32 + r0, c8)] = cvt8(u2, u3);
    }

    const unsigned short* wb1[4];
#pragma unroll
    for (int n = 0; n < 4; ++n)
        wb1[n] = W1t + (size_t)e * NH * NDIN + (size_t)(nb + n * 16 + l16) * NDIN + q * 8;

    bf16x8 bfr[3][4], afr[3][4];
#pragma unroll
    for (int s = 0; s < 2; ++s)
#pragma unroll
        for (int n = 0; n < 4; ++n)
            bfr[s][n] = *(const bf16x8*)(wb1[n] + s * 32);
    float4 b1q[4];
#pragma unroll
    for (int n = 0; n < 4; ++n)
        b1q[n] = *(const float4*)(b1 + e * NH + nb + n * 16 + q * 4);

    __syncthreads();   // sX visible (also drains the W1 prologue loads)

    // ---------------- layer 1: sH = relu(X @ W1 + b1), 4 kt ----------------
    // swapped operands: D[hcol = nb+n*16+q*4+r][xrow = m*16+l16]; bias pre-loaded.
    f32x4 acc[4][4];
#pragma unroll
    for (int n = 0; n < 4; ++n) {
        const f32x4 bi = {b1q[n].x, b1q[n].y, b1q[n].z, b1q[n].w};
#pragma unroll
        for (int m = 0; m < 4; ++m) acc[m][n] = bi;
    }

#pragma unroll
    for (int s = 0; s < 2; ++s)
#pragma unroll
        for (int m = 0; m < 4; ++m)
            afr[s][m] = *(const bf16x8*)&sX[aX[m] + (((s ^ hi2) & 3) << 5)];

#pragma unroll
    for (int kt = 0; kt < 4; ++kt) {
        const int cur = kt % 3, pre = (kt + 2) % 3;
        if (kt < 2) {
#pragma unroll
            for (int n = 0; n < 4; ++n)
                bfr[pre][n] = *(const bf16x8*)(wb1[n] + (kt + 2) * 32);
#pragma unroll
            for (int m = 0; m < 4; ++m)
                afr[pre][m] = *(const bf16x8*)&sX[aX[m] + ((((kt + 2) ^ hi2) & 3) << 5)];
        }
#pragma unroll
        for (int m = 0; m < 4; ++m)
#pragma unroll
            for (int n = 0; n < 4; ++n)
                acc[m][n] = __builtin_amdgcn_mfma_f32_16x16x32_bf16(
                    bfr[cur][n], afr[cur][m], acc[m][n], 0, 0, 0);
    }

    // W2 prologue + b2 in flight over the H1 epilogue + barrier
    const unsigned short* wb2[4];
#pragma unroll
    for (int n = 0; n < 4; ++n)
        wb2[n] = W2t + (size_t)e * NH * NH + (size_t)(nb + n * 16 + l16) * NH + q * 8;
#pragma unroll
    for (int s = 0; s < 2; ++s)
#pragma unroll
        for (int n = 0; n < 4; ++n)
            bfr[s][n] = *(const bf16x8*)(wb2[n] + s * 32);
    float4 b2q[4];
#pragma unroll
    for (int n = 0; n < 4; ++n)
        b2q[n] = *(const float4*)(b2 + e * NH + nb + n * 16 + q * 4);

    // H1 epilogue: per (m,n) 4 consecutive hcols at one row -> one ds_write_b64
#pragma unroll
    for (int n = 0; n < 4; ++n) {
        const int c0 = nb + n * 16 + q * 4;
#pragma unroll
        for (int m = 0; m < 4; ++m) {
            bf16x4 pk;
#pragma unroll
            for (int r = 0; r < 4; ++r) pk[r] = (__bf16)fmaxf(acc[m][n][r], 0.f);
            *(bf16x4*)&sH[shidx(m * 16 + l16, c0)] = pk;
        }
    }
    __syncthreads();   // H1 visible

    // ---------------- layer 2: acc2 = H1 @ W2 (+b2 pre-loaded), 16 kt ----------------
    f32x4 acc2[4][4];
#pragma unroll
    for (int n = 0; n < 4; ++n) {
        const f32x4 bi = {b2q[n].x, b2q[n].y, b2q[n].z, b2q[n].w};
#pragma unroll
        for (int m = 0; m < 4; ++m) acc2[m][n] = bi;
    }

#pragma unroll
    for (int s = 0; s < 2; ++s)
#pragma unroll
        for (int m = 0; m < 4; ++m)
            afr[s][m] = *(const bf16x8*)&sH[aH[m] + (((s ^ hi2)) << 5)];

#pragma unroll
    for (int kt = 0; kt < 16; ++kt) {
        const int cur = kt % 3, pre = (kt + 2) % 3;
        if (kt < 14) {
#pragma unroll
            for (int n = 0; n < 4; ++n)
                bfr[pre][n] = *(const bf16x8*)(wb2[n] + (kt + 2) * 32);
#pragma unroll
            for (int m = 0; m < 4; ++m)
                afr[pre][m] = *(const bf16x8*)&sH[aH[m] + ((((kt + 2) ^ hi2)) << 5)];
        }
#pragma unroll
        for (int m = 0; m < 4; ++m)
#pragma unroll
            for (int n = 0; n < 4; ++n)
                acc2[m][n] = __builtin_amdgcn_mfma_f32_16x16x32_bf16(
                    bfr[cur][n], afr[cur][m], acc2[m][n], 0, 0, 0);
    }

    // L3 mapping: wave -> (m-pair, n-tile): halves W3 dup, 8 waves cover 4x4 tiles.
    const int n3 = wave & 3, mp = wave >> 2;
    // prefetch ALL 16 B3 frags + b3 now; latency hides under epilogue + 2 barriers
    const unsigned short* wb3 = W3t + (size_t)e * NDO * NH + (size_t)(n3 * 16 + l16) * NH + q * 8;
    bf16x8 b3f[16];
#pragma unroll
    for (int kt = 0; kt < 16; ++kt) b3f[kt] = *(const bf16x8*)(wb3 + kt * 32);
    const float b3v = b3[e * NDO + n3 * 16 + l16];

    __syncthreads();   // all H1 reads complete before overwrite

    // H2 epilogue
#pragma unroll
    for (int n = 0; n < 4; ++n) {
        const int c0 = nb + n * 16 + q * 4;
#pragma unroll
        for (int m = 0; m < 4; ++m) {
            bf16x4 pk;
#pragma unroll
            for (int r = 0; r < 4; ++r) pk[r] = (__bf16)fmaxf(acc2[m][n][r], 0.f);
            *(bf16x4*)&sH[shidx(m * 16 + l16, c0)] = pk;
        }
    }
    __syncthreads();   // H2 visible

    // ---------------- layer 3: O = H2 @ W3 (B in regs; A lookahead-3 in 4 slots) ----------------
    int a3[2];
#pragma unroll
    for (int i = 0; i < 2; ++i) a3[i] = ((2 * mp + i) * 16 + l16) * NH + qe;

    bf16x8 a3f[4][2];
#pragma unroll
    for (int s = 0; s < 3; ++s)          // preload chunks 0..2 (slot s = chunk s)
#pragma unroll
        for (int i = 0; i < 2; ++i)
            a3f[s][i] = *(const bf16x8*)&sH[a3[i] + (((s ^ hi2)) << 5)];

    f32x4 oacc[2];
    {
        const f32x4 ob = {b3v, b3v, b3v, b3v};   // bias in accumulator
        oacc[0] = ob; oacc[1] = ob;
    }
#pragma unroll
    for (int kt = 0; kt < 16; ++kt) {
        const int cur = kt & 3;
        if (kt < 13) {                   // prefetch chunk kt+3 into slot (kt+3)&3 != cur
            const int pre = (kt + 3) & 3;
#pragma unroll
            for (int i = 0; i < 2; ++i)
                a3f[pre][i] = *(const bf16x8*)&sH[a3[i] + ((((kt + 3) ^ hi2)) << 5)];
        }
#pragma unroll
        for (int i = 0; i < 2; ++i)
            oacc[i] = __builtin_amdgcn_mfma_f32_16x16x32_bf16(
                a3f[cur][i], b3f[kt], oacc[i], 0, 0, 0);
    }

    // final: per-expert contribution -> global fp32 atomics
#pragma unroll
    for (int i = 0; i < 2; ++i) {
        const int col = n3 * 16 + l16;
#pragma unroll
        for (int r = 0; r < 4; ++r) {
            const int row = b0 + (2 * mp + i) * 16 + q * 4 + r;
            unsafeAtomicAdd(out + (size_t)row * NDO + col, oacc[i][r]);
        }
    }
}

extern "C" void kernel_launch(void* const* d_in, const int* in_sizes, int n_in,
                              void* d_out, int out_size, void* d_ws, size_t ws_size,
                              hipStream_t stream) {
    const float* x  = (const float*)d_in[0];
    const float* W1 = (const float*)d_in[1];
    const float* b1 = (const float*)d_in[2];
    const float* W2 = (const float*)d_in[3];
    const float* b2 = (const float*)d_in[4];
    const float* W3 = (const float*)d_in[5];
    const float* b3 = (const float*)d_in[6];
    float* out = (float*)d_out;

    unsigned short* W1t = (unsigned short*)d_ws;            // [E][H][DIN]
    unsigned short* W2t = W1t + (size_t)NE * NH * NDIN;     // [E][H][H]
    unsigned short* W3t = W2t + (size_t)NE * NH * NH;       // [E][DOUT][H]

    hipMemsetAsync(d_out, 0, (size_t)out_size * sizeof(float), stream);
    prep_weights<<<dim3(88, NE), 256, 0, stream>>>(W1, W2, W3, W1t, W2t, W3t);
    moe_fused<<<dim3((NB / 64) * NE), 512, 0, stream>>>(x, b1, b2, b3, W1t, W2t, W3t, out);
}

// Round 2
// 298.645 us; speedup vs baseline: 1.1672x; 1.1672x over previous
//
#include <hip/hip_runtime.h>

// out[b,o] = sum_e ( relu(relu(x[b,e,:]@W1[e]+b1[e])@W2[e]+b2[e]) @ W3[e] + b3[e] )
// E=16, DIN=128, H=512, DOUT=64, B=8192.  94.5 GFLOP.
//
// R7 = R6 with the launch-bounds spill fixed.
//   R6 bug: __launch_bounds__(512,4) -> compiler treats arg2 as blocks/CU ->
//   VGPR capped at 64 -> massive scratch spill (FETCH 78->219MB, WRITE 33->335MB).
//   LDS (80KB/block) limits us to 2 blocks/CU regardless; (512,2) = VGPR cap 128.
// R6 features kept (previously untested due to the spill):
//  (a) Swapped-operand MFMA in L1/L2: mfma(A=W-frag, B=X/H-frag) -> D[hcol][xrow].
//      Epilogue per (m,n) tile: 4x v_max + cvt_pk pair + ONE ds_write_b64
//      (was 64 scalar ds_write_b16 + manual-RNE). Read patterns unchanged.
//      b64 write bank pattern = 4 accesses/bank = inherent minimum for 8B/lane.
//  (b) Bias folded into accumulator init (acc = broadcast(bias), not fzero).
//  (c) XCD-affinity swizzle: 1-D grid 2048, xcd=lin&7, 2 experts per XCD ->
//      per-XCD weight set 1.4MB fits 4MB L2.

#define NE   16
#define NDIN 128
#define NH   512
#define NDO  64
#define NB   8192

using bf16x8 = __attribute__((ext_vector_type(8))) __bf16;
using bf16x4 = __attribute__((ext_vector_type(4))) __bf16;
using f32x4  = __attribute__((ext_vector_type(4))) float;

__device__ __forceinline__ unsigned short f2bf(float f) {
    union { float f; unsigned u; } v; v.f = f;
    unsigned r = v.u + 0x7FFFu + ((v.u >> 16) & 1u);   // RNE
    return (unsigned short)(r >> 16);
}

// compiler-fusable bf16 conversion (emits v_cvt_pk_bf16_f32 pairs)
__device__ __forceinline__ bf16x8 cvt8(float4 a, float4 b) {
    bf16x8 r;
    r[0] = (__bf16)a.x; r[1] = (__bf16)a.y; r[2] = (__bf16)a.z; r[3] = (__bf16)a.w;
    r[4] = (__bf16)b.x; r[5] = (__bf16)b.y; r[6] = (__bf16)b.z; r[7] = (__bf16)b.w;
    return r;
}

// Swizzled index (ushort units): 16B granules XOR'd by row&15 (0 conflicts measured).
__device__ __forceinline__ int shidx(int m, int n) {          // H tile, stride 512
    return m * NH + (((n >> 3) ^ (m & 15)) << 3) + (n & 7);
}
__device__ __forceinline__ int shx(int m, int n) {            // X tile, stride 128
    return m * NDIN + ((((n >> 3) ^ (m & 15)) & 15) << 3) + (n & 7);
}

// ---------------- merged prep: fp32 [e][R][C] -> bf16 [e][C][R] ----------------
__global__ __launch_bounds__(256) void prep_weights(
    const float* __restrict__ W1, const float* __restrict__ W2, const float* __restrict__ W3,
    unsigned short* __restrict__ W1t, unsigned short* __restrict__ W2t, unsigned short* __restrict__ W3t)
{
    __shared__ float tile[64][65];
    const int t = blockIdx.x, e = blockIdx.y;
    const float* src; unsigned short* dst; int R, C, tr, tc;
    if (t < 16)      { src = W1; dst = W1t; R = NDIN; C = NH;  tr = t >> 3;        tc = t & 7;  }
    else if (t < 80) { src = W2; dst = W2t; R = NH;   C = NH;  tr = (t - 16) >> 3; tc = (t - 16) & 7; }
    else             { src = W3; dst = W3t; R = NH;   C = NDO; tr = t - 80;        tc = 0;      }
    const int r0 = tr * 64, c0 = tc * 64;
    const float* s = src + (size_t)e * R * C;
    unsigned short* d = dst + (size_t)e * R * C;
    const int tt = threadIdx.x;
#pragma unroll
    for (int i = 0; i < 4; ++i) {
        int f = i * 256 + tt;
        int r = f >> 4, c4 = (f & 15) * 4;
        const float4 v = *(const float4*)(s + (size_t)(r0 + r) * C + c0 + c4);
        tile[r][c4 + 0] = v.x; tile[r][c4 + 1] = v.y;
        tile[r][c4 + 2] = v.z; tile[r][c4 + 3] = v.w;
    }
    __syncthreads();
#pragma unroll
    for (int i = 0; i < 4; ++i) {
        int f = i * 256 + tt;
        int cc = f >> 4, rb = (f & 15) * 4;
        ushort4 o;
        o.x = f2bf(tile[rb + 0][cc]);
        o.y = f2bf(tile[rb + 1][cc]);
        o.z = f2bf(tile[rb + 2][cc]);
        o.w = f2bf(tile[rb + 3][cc]);
        *(ushort4*)(d + (size_t)(c0 + cc) * R + r0 + rb) = o;
    }
}

// ---------------- fused 3-layer expert MLP: one expert x 64 rows per WG ----------------
__global__ __launch_bounds__(512, 2) void moe_fused(
    const float* __restrict__ x,            // [B][E][DIN]
    const float* __restrict__ b1,           // [E][H]
    const float* __restrict__ b2,           // [E][H]
    const float* __restrict__ b3,           // [E][DOUT]
    const unsigned short* __restrict__ W1t, // [E][H][DIN]  bf16
    const unsigned short* __restrict__ W2t, // [E][H][H]    bf16
    const unsigned short* __restrict__ W3t, // [E][DOUT][H] bf16
    float* __restrict__ out)                // [B][DOUT]  (pre-zeroed)
{
    __shared__ unsigned short sMem[64 * NDIN + 64 * NH];  // 16KB X + 64KB H = 80KB
    unsigned short* sX = sMem;
    unsigned short* sH = sMem + 64 * NDIN;

    const int tid  = threadIdx.x;
    const int wave = tid >> 6;
    const int lane = tid & 63;
    const int q    = lane >> 4;
    const int l16  = lane & 15;
    const int hi2  = l16 >> 2;
    const int lo2  = l16 & 3;
    const int qe   = (q ^ lo2) * 8;       // swizzled in-granule element offset

    // XCD-affinity decode: dispatch round-robins linear id across the 8 XCDs,
    // so xcd = lin&7.  Give each XCD 2 experts -> weight set stays L2-resident.
    const int lin = blockIdx.x;
    const int e   = ((lin & 7) << 1) | ((lin >> 3) & 1);
    const int b0  = (lin >> 4) << 6;
    const int nb  = wave * 64;

    // per-wave LDS B-frag base offsets (elements);  read addr = base + ((kt^hi2)<<5)
    int aH[4], aX[4];
#pragma unroll
    for (int m = 0; m < 4; ++m) {
        aH[m] = (m * 16 + l16) * NH   + qe;
        aX[m] = (m * 16 + l16) * NDIN + qe;
    }

    // ---- x staging (global fp32 -> bf16 swizzled LDS), W1 prologue in flight ----
    {
        const int r0 = tid >> 4, c8 = (tid & 15) * 8;
        const float* p0 = x + ((size_t)(b0 + r0)      * NE + e) * NDIN + c8;
        const float* p1 = x + ((size_t)(b0 + 32 + r0) * NE + e) * NDIN + c8;
        float4 u0 = *(const float4*)p0, u1 = *(const float4*)(p0 + 4);
        float4 u2 = *(const float4*)p1, u3 = *(const float4*)(p1 + 4);
        *(bf16x8*)&sX[shx(r0, c8)]      = cvt8(u0, u1);
        *(bf16x8*)&sX[shx(32 + r0, c8)] = cvt8(u2, u3);
    }

    const unsigned short* wb1[4];
#pragma unroll
    for (int n = 0; n < 4; ++n)
        wb1[n] = W1t + (size_t)e * NH * NDIN + (size_t)(nb + n * 16 + l16) * NDIN + q * 8;

    bf16x8 bfr[3][4], afr[3][4];
#pragma unroll
    for (int s = 0; s < 2; ++s)
#pragma unroll
        for (int n = 0; n < 4; ++n)
            bfr[s][n] = *(const bf16x8*)(wb1[n] + s * 32);
    float4 b1q[4];
#pragma unroll
    for (int n = 0; n < 4; ++n)
        b1q[n] = *(const float4*)(b1 + e * NH + nb + n * 16 + q * 4);

    __syncthreads();   // sX visible (also drains the W1 prologue loads)

    // ---------------- layer 1: sH = relu(X @ W1 + b1), 4 kt ----------------
    // swapped operands: D[hcol = nb+n*16+q*4+r][xrow = m*16+l16]; bias pre-loaded.
    f32x4 acc[4][4];
#pragma unroll
    for (int n = 0; n < 4; ++n) {
        const f32x4 bi = {b1q[n].x, b1q[n].y, b1q[n].z, b1q[n].w};
#pragma unroll
        for (int m = 0; m < 4; ++m) acc[m][n] = bi;
    }

#pragma unroll
    for (int s = 0; s < 2; ++s)
#pragma unroll
        for (int m = 0; m < 4; ++m)
            afr[s][m] = *(const bf16x8*)&sX[aX[m] + (((s ^ hi2) & 3) << 5)];

#pragma unroll
    for (int kt = 0; kt < 4; ++kt) {
        const int cur = kt % 3, pre = (kt + 2) % 3;
        if (kt < 2) {
#pragma unroll
            for (int n = 0; n < 4; ++n)
                bfr[pre][n] = *(const bf16x8*)(wb1[n] + (kt + 2) * 32);
#pragma unroll
            for (int m = 0; m < 4; ++m)
                afr[pre][m] = *(const bf16x8*)&sX[aX[m] + ((((kt + 2) ^ hi2) & 3) << 5)];
        }
#pragma unroll
        for (int m = 0; m < 4; ++m)
#pragma unroll
            for (int n = 0; n < 4; ++n)
                acc[m][n] = __builtin_amdgcn_mfma_f32_16x16x32_bf16(
                    bfr[cur][n], afr[cur][m], acc[m][n], 0, 0, 0);
    }

    // W2 prologue + b2 in flight over the H1 epilogue + barrier
    const unsigned short* wb2[4];
#pragma unroll
    for (int n = 0; n < 4; ++n)
        wb2[n] = W2t + (size_t)e * NH * NH + (size_t)(nb + n * 16 + l16) * NH + q * 8;
#pragma unroll
    for (int s = 0; s < 2; ++s)
#pragma unroll
        for (int n = 0; n < 4; ++n)
            bfr[s][n] = *(const bf16x8*)(wb2[n] + s * 32);
    float4 b2q[4];
#pragma unroll
    for (int n = 0; n < 4; ++n)
        b2q[n] = *(const float4*)(b2 + e * NH + nb + n * 16 + q * 4);

    // H1 epilogue: per (m,n) 4 consecutive hcols at one row -> one ds_write_b64
#pragma unroll
    for (int n = 0; n < 4; ++n) {
        const int c0 = nb + n * 16 + q * 4;
#pragma unroll
        for (int m = 0; m < 4; ++m) {
            bf16x4 pk;
#pragma unroll
            for (int r = 0; r < 4; ++r) pk[r] = (__bf16)fmaxf(acc[m][n][r], 0.f);
            *(bf16x4*)&sH[shidx(m * 16 + l16, c0)] = pk;
        }
    }
    __syncthreads();   // H1 visible

    // ---------------- layer 2: acc2 = H1 @ W2 (+b2 pre-loaded), 16 kt ----------------
    f32x4 acc2[4][4];
#pragma unroll
    for (int n = 0; n < 4; ++n) {
        const f32x4 bi = {b2q[n].x, b2q[n].y, b2q[n].z, b2q[n].w};
#pragma unroll
        for (int m = 0; m < 4; ++m) acc2[m][n] = bi;
    }

#pragma unroll
    for (int s = 0; s < 2; ++s)
#pragma unroll
        for (int m = 0; m < 4; ++m)
            afr[s][m] = *(const bf16x8*)&sH[aH[m] + (((s ^ hi2)) << 5)];

#pragma unroll
    for (int kt = 0; kt < 16; ++kt) {
        const int cur = kt % 3, pre = (kt + 2) % 3;
        if (kt < 14) {
#pragma unroll
            for (int n = 0; n < 4; ++n)
                bfr[pre][n] = *(const bf16x8*)(wb2[n] + (kt + 2) * 32);
#pragma unroll
            for (int m = 0; m < 4; ++m)
                afr[pre][m] = *(const bf16x8*)&sH[aH[m] + ((((kt + 2) ^ hi2)) << 5)];
        }
#pragma unroll
        for (int m = 0; m < 4; ++m)
#pragma unroll
            for (int n = 0; n < 4; ++n)
                acc2[m][n] = __builtin_amdgcn_mfma_f32_16x16x32_bf16(
                    bfr[cur][n], afr[cur][m], acc2[m][n], 0, 0, 0);
    }

    // L3 mapping: wave -> (m-pair, n-tile): halves W3 dup, 8 waves cover 4x4 tiles.
    const int n3 = wave & 3, mp = wave >> 2;
    // prefetch ALL 16 B3 frags + b3 now; latency hides under epilogue + 2 barriers
    const unsigned short* wb3 = W3t + (size_t)e * NDO * NH + (size_t)(n3 * 16 + l16) * NH + q * 8;
    bf16x8 b3f[16];
#pragma unroll
    for (int kt = 0; kt < 16; ++kt) b3f[kt] = *(const bf16x8*)(wb3 + kt * 32);
    const float b3v = b3[e * NDO + n3 * 16 + l16];

    __syncthreads();   // all H1 reads complete before overwrite

    // H2 epilogue
#pragma unroll
    for (int n = 0; n < 4; ++n) {
        const int c0 = nb + n * 16 + q * 4;
#pragma unroll
        for (int m = 0; m < 4; ++m) {
            bf16x4 pk;
#pragma unroll
            for (int r = 0; r < 4; ++r) pk[r] = (__bf16)fmaxf(acc2[m][n][r], 0.f);
            *(bf16x4*)&sH[shidx(m * 16 + l16, c0)] = pk;
        }
    }
    __syncthreads();   // H2 visible

    // ---------------- layer 3: O = H2 @ W3 (B in regs; A lookahead-3 in 4 slots) ----------------
    int a3[2];
#pragma unroll
    for (int i = 0; i < 2; ++i) a3[i] = ((2 * mp + i) * 16 + l16) * NH + qe;

    bf16x8 a3f[4][2];
#pragma unroll
    for (int s = 0; s < 3; ++s)          // preload chunks 0..2 (slot s = chunk s)
#pragma unroll
        for (int i = 0; i < 2; ++i)
            a3f[s][i] = *(const bf16x8*)&sH[a3[i] + (((s ^ hi2)) << 5)];

    f32x4 oacc[2];
    {
        const f32x4 ob = {b3v, b3v, b3v, b3v};   // bias in accumulator
        oacc[0] = ob; oacc[1] = ob;
    }
#pragma unroll
    for (int kt = 0; kt < 16; ++kt) {
        const int cur = kt & 3;
        if (kt < 13) {                   // prefetch chunk kt+3 into slot (kt+3)&3 != cur
            const int pre = (kt + 3) & 3;
#pragma unroll
            for (int i = 0; i < 2; ++i)
                a3f[pre][i] = *(const bf16x8*)&sH[a3[i] + ((((kt + 3) ^ hi2)) << 5)];
        }
#pragma unroll
        for (int i = 0; i < 2; ++i)
            oacc[i] = __builtin_amdgcn_mfma_f32_16x16x32_bf16(
                a3f[cur][i], b3f[kt], oacc[i], 0, 0, 0);
    }

    // final: per-expert contribution -> global fp32 atomics
#pragma unroll
    for (int i = 0; i < 2; ++i) {
        const int col = n3 * 16 + l16;
#pragma unroll
        for (int r = 0; r < 4; ++r) {
            const int row = b0 + (2 * mp + i) * 16 + q * 4 + r;
            unsafeAtomicAdd(out + (size_t)row * NDO + col, oacc[i][r]);
        }
    }
}

extern "C" void kernel_launch(void* const* d_in, const int* in_sizes, int n_in,
                              void* d_out, int out_size, void* d_ws, size_t ws_size,
                              hipStream_t stream) {
    const float* x  = (const float*)d_in[0];
    const float* W1 = (const float*)d_in[1];
    const float* b1 = (const float*)d_in[2];
    const float* W2 = (const float*)d_in[3];
    const float* b2 = (const float*)d_in[4];
    const float* W3 = (const float*)d_in[5];
    const float* b3 = (const float*)d_in[6];
    float* out = (float*)d_out;

    unsigned short* W1t = (unsigned short*)d_ws;            // [E][H][DIN]
    unsigned short* W2t = W1t + (size_t)NE * NH * NDIN;     // [E][H][H]
    unsigned short* W3t = W2t + (size_t)NE * NH * NH;       // [E][DOUT][H]

    hipMemsetAsync(d_out, 0, (size_t)out_size * sizeof(float), stream);
    prep_weights<<<dim3(88, NE), 256, 0, stream>>>(W1, W2, W3, W1t, W2t, W3t);
    moe_fused<<<dim3((NB / 64) * NE), 512, 0, stream>>>(x, b1, b2, b3, W1t, W2t, W3t, out);
}